// Round 1
// baseline (425.199 us; speedup 1.0000x reference)
//
#include <hip/hip_runtime.h>
#include <math.h>

// Problem constants
#define T_LEN 2048
#define BB    8
#define RS    256
#define DIN   1024
#define NE    768                 // 256 (W_proj) + 512 (W_res)
#define M_TOT (BB * T_LEN)        // 16384
#define LCH   32                  // scan chunk length
#define NCH   (T_LEN / LCH)       // 64 chunks
#define OUT_MAIN (M_TOT * 512)    // 8388608 floats, then final_r (2048), final_i (2048)

// ---------------------------------------------------------------------------
// K1: fused GEMM  C[m][n] = dot(u[m, :], Wcat[n, :])
//     u: (16384, 1024) row-major (B*T collapsed), Wcat rows 0..255 = W_proj,
//     rows 256..767 = W_res. FP32 vector-ALU, 128x128 tile, 8x8 microtile.
// ---------------------------------------------------------------------------
__global__ __launch_bounds__(256) void gemm_kernel(
    const float* __restrict__ U, const float* __restrict__ Wp,
    const float* __restrict__ Wr, float* __restrict__ C)
{
    __shared__ float As[16][132];   // [k][m], stride 132 floats: 16B-aligned rows, bank-spread
    __shared__ float Bs[16][132];   // [k][n]
    const int tid  = threadIdx.x;
    const int bm   = blockIdx.x;    // 0..127
    const int bn   = blockIdx.y;    // 0..5
    const int tx   = tid & 15;
    const int ty   = tid >> 4;
    const int lrow = tid >> 2;          // 0..63
    const int lcol = (tid & 3) << 2;    // 0,4,8,12

    const float* Ap0 = U + (size_t)(bm * 128 + lrow) * DIN + lcol;
    const float* Ap1 = Ap0 + (size_t)64 * DIN;
    const int n0 = bn * 128 + lrow;          // tile never straddles the 256 boundary
    const int n1 = n0 + 64;
    const float* Bp0 = (n0 < RS) ? (Wp + (size_t)n0 * DIN + lcol)
                                 : (Wr + (size_t)(n0 - RS) * DIN + lcol);
    const float* Bp1 = (n1 < RS) ? (Wp + (size_t)n1 * DIN + lcol)
                                 : (Wr + (size_t)(n1 - RS) * DIN + lcol);

    float acc[8][8];
#pragma unroll
    for (int i = 0; i < 8; ++i)
#pragma unroll
        for (int j = 0; j < 8; ++j) acc[i][j] = 0.f;

    for (int kk = 0; kk < DIN; kk += 16) {
        const float4 a0 = *(const float4*)(Ap0 + kk);
        const float4 a1 = *(const float4*)(Ap1 + kk);
        const float4 b0 = *(const float4*)(Bp0 + kk);
        const float4 b1 = *(const float4*)(Bp1 + kk);
        __syncthreads();   // previous iteration's readers done before overwrite
        As[lcol + 0][lrow]      = a0.x; As[lcol + 1][lrow]      = a0.y;
        As[lcol + 2][lrow]      = a0.z; As[lcol + 3][lrow]      = a0.w;
        As[lcol + 0][lrow + 64] = a1.x; As[lcol + 1][lrow + 64] = a1.y;
        As[lcol + 2][lrow + 64] = a1.z; As[lcol + 3][lrow + 64] = a1.w;
        Bs[lcol + 0][lrow]      = b0.x; Bs[lcol + 1][lrow]      = b0.y;
        Bs[lcol + 2][lrow]      = b0.z; Bs[lcol + 3][lrow]      = b0.w;
        Bs[lcol + 0][lrow + 64] = b1.x; Bs[lcol + 1][lrow + 64] = b1.y;
        Bs[lcol + 2][lrow + 64] = b1.z; Bs[lcol + 3][lrow + 64] = b1.w;
        __syncthreads();
#pragma unroll
        for (int k = 0; k < 16; ++k) {
            const float4 av0 = *(const float4*)&As[k][ty * 4];
            const float4 av1 = *(const float4*)&As[k][ty * 4 + 64];
            const float4 bv0 = *(const float4*)&Bs[k][tx * 4];
            const float4 bv1 = *(const float4*)&Bs[k][tx * 4 + 64];
            const float a[8]  = {av0.x, av0.y, av0.z, av0.w, av1.x, av1.y, av1.z, av1.w};
            const float bv[8] = {bv0.x, bv0.y, bv0.z, bv0.w, bv1.x, bv1.y, bv1.z, bv1.w};
#pragma unroll
            for (int i = 0; i < 8; ++i)
#pragma unroll
                for (int j = 0; j < 8; ++j)
                    acc[i][j] = fmaf(a[i], bv[j], acc[i][j]);
        }
    }

#pragma unroll
    for (int ih = 0; ih < 2; ++ih)
#pragma unroll
        for (int ii = 0; ii < 4; ++ii) {
            const int m = bm * 128 + ih * 64 + ty * 4 + ii;
#pragma unroll
            for (int jh = 0; jh < 2; ++jh) {
                const float4 v = make_float4(acc[ih * 4 + ii][jh * 4 + 0],
                                             acc[ih * 4 + ii][jh * 4 + 1],
                                             acc[ih * 4 + ii][jh * 4 + 2],
                                             acc[ih * 4 + ii][jh * 4 + 3]);
                *(float4*)&C[(size_t)m * NE + bn * 128 + jh * 64 + tx * 4] = v;
            }
        }
}

// ---------------------------------------------------------------------------
// complex pole per state r:  z = exp(lam) * (cos w, sin w),  lam = -5*sigmoid(lraw)
// ---------------------------------------------------------------------------
__device__ inline void pole(const float* __restrict__ lraw, const float* __restrict__ om,
                            int r, float& zr, float& zi, float& lam, float& o)
{
    const float x   = lraw[r];
    const float sig = 1.f / (1.f + expf(-x));
    lam = -5.f * sig;
    o   = om[r];
    const float er = expf(lam);
    zr = er * cosf(o);
    zi = er * sinf(o);
}

// ---------------------------------------------------------------------------
// K2: per-chunk carries (scan with zero init over each length-32 chunk)
//     block = (chunk c, batch b), thread = state r
// ---------------------------------------------------------------------------
__global__ __launch_bounds__(256) void carry_kernel(
    const float* __restrict__ C, const float* __restrict__ lraw,
    const float* __restrict__ om, float2* __restrict__ carry)
{
    const int c = blockIdx.x, b = blockIdx.y, r = threadIdx.x;
    __shared__ float tile[LCH][RS];
    const int m0 = b * T_LEN + c * LCH;
    for (int s = 0; s < LCH; ++s)
        tile[s][r] = C[(size_t)(m0 + s) * NE + r];
    float zr, zi, lam, o;
    pole(lraw, om, r, zr, zi, lam, o);
    __syncthreads();
    float hr = 0.f, hi = 0.f;
#pragma unroll 4
    for (int s = 0; s < LCH; ++s) {
        const float u  = tile[s][r];
        const float nr = zr * hr - zi * hi + u;
        const float ni = zr * hi + zi * hr;
        hr = nr; hi = ni;
    }
    carry[(size_t)(b * NCH + c) * RS + r] = make_float2(hr, hi);
}

// ---------------------------------------------------------------------------
// K3: prefix over chunks per (b, r). S[c] = state entering chunk c (h[-1]=h0).
//     Also writes final_r/final_i (= h[T-1]) to the output tail.
// ---------------------------------------------------------------------------
__global__ __launch_bounds__(256) void chunk_scan_kernel(
    const float2* __restrict__ carry, const float* __restrict__ h0r,
    const float* __restrict__ h0i, const float* __restrict__ lraw,
    const float* __restrict__ om, float2* __restrict__ S, float* __restrict__ out)
{
    const int b = blockIdx.x, r = threadIdx.x;
    float zr, zi, lam, o;
    pole(lraw, om, r, zr, zi, lam, o);
    const float eL  = expf(lam * (float)LCH);
    const float zLr = eL * cosf(o * (float)LCH);
    const float zLi = eL * sinf(o * (float)LCH);
    float sr = h0r[b * RS + r];
    float si = h0i[b * RS + r];
    for (int c = 0; c < NCH; ++c) {
        S[(size_t)(b * NCH + c) * RS + r] = make_float2(sr, si);
        const float2 cc = carry[(size_t)(b * NCH + c) * RS + r];
        const float nr = zLr * sr - zLi * si + cc.x;
        const float ni = zLr * si + zLi * sr + cc.y;
        sr = nr; si = ni;
    }
    out[OUT_MAIN + b * RS + r]            = sr;   // final_r
    out[OUT_MAIN + BB * RS + b * RS + r]  = si;   // final_i
}

// ---------------------------------------------------------------------------
// K4: re-scan chunk with proper initial state, add residual, LayerNorm, store.
//     block = (chunk c, batch b), thread = state r (owns out cols r and r+256)
// ---------------------------------------------------------------------------
__global__ __launch_bounds__(256) void scan_ln_kernel(
    const float* __restrict__ C, const float2* __restrict__ S,
    const float* __restrict__ lraw, const float* __restrict__ om,
    const float* __restrict__ gamma, const float* __restrict__ beta,
    float* __restrict__ out)
{
    const int c = blockIdx.x, b = blockIdx.y, r = threadIdx.x;
    __shared__ float tile[LCH][RS];
    __shared__ float redA[4], redB[4];
    const int m0 = b * T_LEN + c * LCH;
    for (int s = 0; s < LCH; ++s)
        tile[s][r] = C[(size_t)(m0 + s) * NE + r];
    float zr, zi, lam, o;
    pole(lraw, om, r, zr, zi, lam, o);
    float2 st = S[(size_t)(b * NCH + c) * RS + r];
    const float g1 = gamma[r], g2 = gamma[RS + r];
    const float b1 = beta[r],  b2 = beta[RS + r];
    const int wid = r >> 6, lane = r & 63;
    __syncthreads();

    for (int s = 0; s < LCH; ++s) {
        const float u  = tile[s][r];
        const float hr = zr * st.x - zi * st.y + u;
        const float hi = zr * st.y + zi * st.x;
        st.x = hr; st.y = hi;
        const int m = m0 + s;
        const float x1 = hr + C[(size_t)m * NE + 256 + r];
        const float x2 = hi + C[(size_t)m * NE + 512 + r];
        float s1 = x1 + x2;
        float s2 = x1 * x1 + x2 * x2;
#pragma unroll
        for (int off = 1; off < 64; off <<= 1) {
            s1 += __shfl_xor(s1, off);
            s2 += __shfl_xor(s2, off);
        }
        if (lane == 0) { redA[wid] = s1; redB[wid] = s2; }
        __syncthreads();
        s1 = redA[0] + redA[1] + redA[2] + redA[3];
        s2 = redB[0] + redB[1] + redB[2] + redB[3];
        const float mu   = s1 * (1.f / 512.f);
        const float var  = s2 * (1.f / 512.f) - mu * mu;
        const float rstd = rsqrtf(var + 1e-5f);
        out[(size_t)m * 512 + r]       = (x1 - mu) * rstd * g1 + b1;
        out[(size_t)m * 512 + 256 + r] = (x2 - mu) * rstd * g2 + b2;
        __syncthreads();   // red[] reuse next iteration
    }
}

// ---------------------------------------------------------------------------
extern "C" void kernel_launch(void* const* d_in, const int* in_sizes, int n_in,
                              void* d_out, int out_size, void* d_ws, size_t ws_size,
                              hipStream_t stream)
{
    const float* u    = (const float*)d_in[0];
    const float* h0r  = (const float*)d_in[1];
    const float* h0i  = (const float*)d_in[2];
    const float* lraw = (const float*)d_in[3];
    const float* omg  = (const float*)d_in[4];
    const float* Wp   = (const float*)d_in[5];
    const float* Wr   = (const float*)d_in[6];
    const float* gam  = (const float*)d_in[7];
    const float* bet  = (const float*)d_in[8];
    float* out = (float*)d_out;

    float*  C     = (float*)d_ws;                       // 16384*768 floats (50.3 MB)
    float2* carry = (float2*)(C + (size_t)M_TOT * NE);  // B*NCH*RS float2 (1 MB)
    float2* S     = carry + (size_t)BB * NCH * RS;      // B*NCH*RS float2 (1 MB)

    gemm_kernel<<<dim3(M_TOT / 128, NE / 128), 256, 0, stream>>>(u, Wp, Wr, C);
    carry_kernel<<<dim3(NCH, BB), 256, 0, stream>>>(C, lraw, omg, carry);
    chunk_scan_kernel<<<BB, 256, 0, stream>>>(carry, h0r, h0i, lraw, omg, S, out);
    scan_ln_kernel<<<dim3(NCH, BB), 256, 0, stream>>>(C, (const float2*)S, lraw, omg, gam, bet, out);
}

// Round 2
// 256.535 us; speedup vs baseline: 1.6575x; 1.6575x over previous
//
#include <hip/hip_runtime.h>
#include <math.h>

// Problem constants
#define T_LEN 2048
#define BB    8
#define RS    256
#define DIN   1024
#define NE    768                 // 256 (W_proj) + 512 (W_res)
#define M_TOT (BB * T_LEN)        // 16384
#define LCH   32                  // scan chunk length
#define NCH   (T_LEN / LCH)       // 64 chunks
#define OUT_MAIN (M_TOT * 512)    // 8388608 floats, then final_r (2048), final_i (2048)

typedef unsigned short ushort;
typedef unsigned int   uint;
typedef short  short8  __attribute__((ext_vector_type(8)));
typedef float  f32x4   __attribute__((ext_vector_type(4)));
typedef ushort ushort8 __attribute__((ext_vector_type(8)));

// round-to-nearest-even fp32 -> bf16 bits
__device__ __forceinline__ ushort f2bf_rn(float x) {
    uint u = __float_as_uint(x);
    return (ushort)((u + 0x7FFFu + ((u >> 16) & 1u)) >> 16);
}
__device__ __forceinline__ float bf2f(ushort b) {
    return __uint_as_float(((uint)b) << 16);
}

// async global->LDS, 16 bytes per lane (lane-linear LDS dest required)
__device__ __forceinline__ void gload16(const ushort* g, ushort* l) {
    __builtin_amdgcn_global_load_lds(
        (const __attribute__((address_space(1))) uint*)g,
        (__attribute__((address_space(3))) uint*)l, 16, 0, 0);
}

// ---------------------------------------------------------------------------
// K0: split fp32 -> bf16 hi/lo planes (memory-bound, vectorized 8 floats/thread)
// ---------------------------------------------------------------------------
__global__ __launch_bounds__(256) void split_kernel(
    const float* __restrict__ src, ushort* __restrict__ hi,
    ushort* __restrict__ lo, int n8)
{
    int i = blockIdx.x * blockDim.x + threadIdx.x;
    const int stride = gridDim.x * blockDim.x;
    for (; i < n8; i += stride) {
        const float4 x0 = ((const float4*)src)[(size_t)i * 2 + 0];
        const float4 x1 = ((const float4*)src)[(size_t)i * 2 + 1];
        const float xs[8] = {x0.x, x0.y, x0.z, x0.w, x1.x, x1.y, x1.z, x1.w};
        ushort8 hv, lv;
#pragma unroll
        for (int j = 0; j < 8; ++j) {
            const ushort hb = f2bf_rn(xs[j]);
            hv[j] = hb;
            lv[j] = f2bf_rn(xs[j] - bf2f(hb));
        }
        ((ushort8*)hi)[i] = hv;
        ((ushort8*)lo)[i] = lv;
    }
}

// ---------------------------------------------------------------------------
// K1: bf16 3-term split MFMA GEMM.  C[m][n] = dot(U[m,:], Wcat[n,:])
//     m97 structure: 128x128 tile, BK=32, 4 waves (2x2), 4x4 16x16x32 frags,
//     global_load_lds width=16 staging, 2-barrier K-loop.
// ---------------------------------------------------------------------------
#define Bb 128
#define BK 32

__global__ __launch_bounds__(256) void gemm_mfma(
    const ushort* __restrict__ Uh, const ushort* __restrict__ Ul,
    const ushort* __restrict__ Wh, const ushort* __restrict__ Wl,
    float* __restrict__ C)
{
    __shared__ ushort Ah[Bb * BK], Al[Bb * BK], Bh[Bb * BK], Bl[Bb * BK];
    const int tid  = threadIdx.x;
    const int bn   = blockIdx.x;          // 0..5
    const int bm   = blockIdx.y;          // 0..127
    const int wid  = tid >> 6;
    const int lane = tid & 63;
    const int wr   = wid >> 1, wc = wid & 1;
    const int fr   = lane & 15;           // row/col within fragment
    const int fq   = lane >> 4;           // k-chunk 0..3

    // staging: thread t covers elements t*8..t*8+7 of each 128x32 plane (round 0:
    // rows 0..63, round 1: rows 64..127) — lane-linear LDS dest for global_load_lds.
    const int srow = tid >> 2;            // 0..63
    const int skk  = (tid & 3) * 8;
    const ushort* gAh = Uh + (size_t)(bm * 128 + srow) * DIN + skk;
    const ushort* gAl = Ul + (size_t)(bm * 128 + srow) * DIN + skk;
    const ushort* gBh = Wh + (size_t)(bn * 128 + srow) * DIN + skk;
    const ushort* gBl = Wl + (size_t)(bn * 128 + srow) * DIN + skk;
    ushort* lAh0 = Ah + tid * 8; ushort* lAh1 = Ah + 64 * BK + tid * 8;
    ushort* lAl0 = Al + tid * 8; ushort* lAl1 = Al + 64 * BK + tid * 8;
    ushort* lBh0 = Bh + tid * 8; ushort* lBh1 = Bh + 64 * BK + tid * 8;
    ushort* lBl0 = Bl + tid * 8; ushort* lBl1 = Bl + 64 * BK + tid * 8;
    const size_t rstep = (size_t)64 * DIN;

    f32x4 acc[4][4];
#pragma unroll
    for (int m = 0; m < 4; ++m)
#pragma unroll
        for (int n = 0; n < 4; ++n) acc[m][n] = (f32x4){0.f, 0.f, 0.f, 0.f};

    for (int kk = 0; kk < DIN; kk += BK) {
        gload16(gAh + kk, lAh0); gload16(gAh + kk + rstep, lAh1);
        gload16(gAl + kk, lAl0); gload16(gAl + kk + rstep, lAl1);
        gload16(gBh + kk, lBh0); gload16(gBh + kk + rstep, lBh1);
        gload16(gBl + kk, lBl0); gload16(gBl + kk + rstep, lBl1);
        __syncthreads();   // drains vmcnt (compiler-emitted) — tiles ready

        short8 ah[4], al[4], bh[4], bl[4];
#pragma unroll
        for (int m = 0; m < 4; ++m) {
            const int row = wr * 64 + m * 16 + fr;
            ah[m] = *(const short8*)&Ah[row * BK + fq * 8];
            al[m] = *(const short8*)&Al[row * BK + fq * 8];
        }
#pragma unroll
        for (int n = 0; n < 4; ++n) {
            const int col = wc * 64 + n * 16 + fr;
            bh[n] = *(const short8*)&Bh[col * BK + fq * 8];
            bl[n] = *(const short8*)&Bl[col * BK + fq * 8];
        }
#pragma unroll
        for (int m = 0; m < 4; ++m)
#pragma unroll
            for (int n = 0; n < 4; ++n) {
                acc[m][n] = __builtin_amdgcn_mfma_f32_16x16x32_bf16(ah[m], bh[n], acc[m][n], 0, 0, 0);
                acc[m][n] = __builtin_amdgcn_mfma_f32_16x16x32_bf16(ah[m], bl[n], acc[m][n], 0, 0, 0);
                acc[m][n] = __builtin_amdgcn_mfma_f32_16x16x32_bf16(al[m], bh[n], acc[m][n], 0, 0, 0);
            }
        __syncthreads();   // readers done before next overwrite
    }

    // epilogue: C/D layout col=lane&15, row=(lane>>4)*4+reg  [m89/m91]
    const int crow0 = bm * 128 + wr * 64;
    const int ccol0 = bn * 128 + wc * 64;
#pragma unroll
    for (int m = 0; m < 4; ++m) {
        const int row = crow0 + m * 16 + fq * 4;
#pragma unroll
        for (int n = 0; n < 4; ++n) {
            const int col = ccol0 + n * 16 + fr;
#pragma unroll
            for (int j = 0; j < 4; ++j)
                C[(size_t)(row + j) * NE + col] = acc[m][n][j];
        }
    }
}

// ---------------------------------------------------------------------------
// complex pole per state r:  z = exp(lam) * (cos w, sin w),  lam = -5*sigmoid(lraw)
// ---------------------------------------------------------------------------
__device__ inline void pole(const float* __restrict__ lraw, const float* __restrict__ om,
                            int r, float& zr, float& zi, float& lam, float& o)
{
    const float x   = lraw[r];
    const float sig = 1.f / (1.f + expf(-x));
    lam = -5.f * sig;
    o   = om[r];
    const float er = expf(lam);
    zr = er * cosf(o);
    zi = er * sinf(o);
}

// ---------------------------------------------------------------------------
// K2: per-chunk carries (scan with zero init over each length-32 chunk)
// ---------------------------------------------------------------------------
__global__ __launch_bounds__(256) void carry_kernel(
    const float* __restrict__ C, const float* __restrict__ lraw,
    const float* __restrict__ om, float2* __restrict__ carry)
{
    const int c = blockIdx.x, b = blockIdx.y, r = threadIdx.x;
    __shared__ float tile[LCH][RS];
    const int m0 = b * T_LEN + c * LCH;
    for (int s = 0; s < LCH; ++s)
        tile[s][r] = C[(size_t)(m0 + s) * NE + r];
    float zr, zi, lam, o;
    pole(lraw, om, r, zr, zi, lam, o);
    __syncthreads();
    float hr = 0.f, hi = 0.f;
#pragma unroll 4
    for (int s = 0; s < LCH; ++s) {
        const float u  = tile[s][r];
        const float nr = zr * hr - zi * hi + u;
        const float ni = zr * hi + zi * hr;
        hr = nr; hi = ni;
    }
    carry[(size_t)(b * NCH + c) * RS + r] = make_float2(hr, hi);
}

// ---------------------------------------------------------------------------
// K3: prefix over chunks per (b, r). Also writes final_r/final_i.
// ---------------------------------------------------------------------------
__global__ __launch_bounds__(256) void chunk_scan_kernel(
    const float2* __restrict__ carry, const float* __restrict__ h0r,
    const float* __restrict__ h0i, const float* __restrict__ lraw,
    const float* __restrict__ om, float2* __restrict__ S, float* __restrict__ out)
{
    const int b = blockIdx.x, r = threadIdx.x;
    float zr, zi, lam, o;
    pole(lraw, om, r, zr, zi, lam, o);
    const float eL  = expf(lam * (float)LCH);
    const float zLr = eL * cosf(o * (float)LCH);
    const float zLi = eL * sinf(o * (float)LCH);
    float sr = h0r[b * RS + r];
    float si = h0i[b * RS + r];
    for (int c = 0; c < NCH; ++c) {
        S[(size_t)(b * NCH + c) * RS + r] = make_float2(sr, si);
        const float2 cc = carry[(size_t)(b * NCH + c) * RS + r];
        const float nr = zLr * sr - zLi * si + cc.x;
        const float ni = zLr * si + zLi * sr + cc.y;
        sr = nr; si = ni;
    }
    out[OUT_MAIN + b * RS + r]            = sr;   // final_r
    out[OUT_MAIN + BB * RS + b * RS + r]  = si;   // final_i
}

// ---------------------------------------------------------------------------
// K4: re-scan chunk with proper initial state, add residual, LayerNorm, store.
// ---------------------------------------------------------------------------
__global__ __launch_bounds__(256) void scan_ln_kernel(
    const float* __restrict__ C, const float2* __restrict__ S,
    const float* __restrict__ lraw, const float* __restrict__ om,
    const float* __restrict__ gamma, const float* __restrict__ beta,
    float* __restrict__ out)
{
    const int c = blockIdx.x, b = blockIdx.y, r = threadIdx.x;
    __shared__ float tile[LCH][RS];
    __shared__ float redA[4], redB[4];
    const int m0 = b * T_LEN + c * LCH;
    for (int s = 0; s < LCH; ++s)
        tile[s][r] = C[(size_t)(m0 + s) * NE + r];
    float zr, zi, lam, o;
    pole(lraw, om, r, zr, zi, lam, o);
    float2 st = S[(size_t)(b * NCH + c) * RS + r];
    const float g1 = gamma[r], g2 = gamma[RS + r];
    const float b1 = beta[r],  b2 = beta[RS + r];
    const int wid = r >> 6, lane = r & 63;
    __syncthreads();

    for (int s = 0; s < LCH; ++s) {
        const float u  = tile[s][r];
        const float hr = zr * st.x - zi * st.y + u;
        const float hi = zr * st.y + zi * st.x;
        st.x = hr; st.y = hi;
        const int m = m0 + s;
        const float x1 = hr + C[(size_t)m * NE + 256 + r];
        const float x2 = hi + C[(size_t)m * NE + 512 + r];
        float s1 = x1 + x2;
        float s2 = x1 * x1 + x2 * x2;
#pragma unroll
        for (int off = 1; off < 64; off <<= 1) {
            s1 += __shfl_xor(s1, off);
            s2 += __shfl_xor(s2, off);
        }
        if (lane == 0) { redA[wid] = s1; redB[wid] = s2; }
        __syncthreads();
        s1 = redA[0] + redA[1] + redA[2] + redA[3];
        s2 = redB[0] + redB[1] + redB[2] + redB[3];
        const float mu   = s1 * (1.f / 512.f);
        const float var  = s2 * (1.f / 512.f) - mu * mu;
        const float rstd = rsqrtf(var + 1e-5f);
        out[(size_t)m * 512 + r]       = (x1 - mu) * rstd * g1 + b1;
        out[(size_t)m * 512 + 256 + r] = (x2 - mu) * rstd * g2 + b2;
        __syncthreads();   // red[] reuse next iteration
    }
}

// ---------------------------------------------------------------------------
extern "C" void kernel_launch(void* const* d_in, const int* in_sizes, int n_in,
                              void* d_out, int out_size, void* d_ws, size_t ws_size,
                              hipStream_t stream)
{
    const float* u    = (const float*)d_in[0];
    const float* h0r  = (const float*)d_in[1];
    const float* h0i  = (const float*)d_in[2];
    const float* lraw = (const float*)d_in[3];
    const float* omg  = (const float*)d_in[4];
    const float* Wp   = (const float*)d_in[5];
    const float* Wr   = (const float*)d_in[6];
    const float* gam  = (const float*)d_in[7];
    const float* bet  = (const float*)d_in[8];
    float* out = (float*)d_out;

    // workspace layout (~123 MB):
    float*  C     = (float*)d_ws;                       // 16384*768 f32 (50.3 MB)
    float2* carry = (float2*)(C + (size_t)M_TOT * NE);  // 1 MB
    float2* S     = carry + (size_t)BB * NCH * RS;      // 1 MB
    ushort* Uhi   = (ushort*)(S + (size_t)BB * NCH * RS);
    ushort* Ulo   = Uhi + (size_t)M_TOT * DIN;          // 33.5 MB each
    ushort* Whi   = Ulo + (size_t)M_TOT * DIN;          // 1.57 MB
    ushort* Wlo   = Whi + (size_t)NE * DIN;             // 1.57 MB

    // K0: split fp32 -> bf16 hi/lo (U, then W_proj and W_res into Wcat planes)
    split_kernel<<<2048, 256, 0, stream>>>(u, Uhi, Ulo, M_TOT * DIN / 8);
    split_kernel<<<128, 256, 0, stream>>>(Wp, Whi, Wlo, RS * DIN / 8);
    split_kernel<<<128, 256, 0, stream>>>(Wr, Whi + (size_t)RS * DIN,
                                          Wlo + (size_t)RS * DIN, 2 * RS * DIN / 8);

    // K1: MFMA GEMM
    gemm_mfma<<<dim3(NE / 128, M_TOT / 128), 256, 0, stream>>>(Uhi, Ulo, Whi, Wlo, C);

    // K2-K4: chunked scan + LN (unchanged from R1)
    carry_kernel<<<dim3(NCH, BB), 256, 0, stream>>>(C, lraw, omg, carry);
    chunk_scan_kernel<<<BB, 256, 0, stream>>>(carry, h0r, h0i, lraw, omg, S, out);
    scan_ln_kernel<<<dim3(NCH, BB), 256, 0, stream>>>(C, (const float2*)S, lraw, omg, gam, bet, out);
}